// Round 1
// baseline (11702.663 us; speedup 1.0000x reference)
//
#include <hip/hip_runtime.h>
#include <hip/hip_bf16.h>

// PBRNN LSTM: B=64, S=512, D=544, H=1024. out = [h_n; c_n] fp32 [2,64,1024].
//
// Design:
//  - cvt_x: X fp32 -> bf16 into ws (35.7 MB).
//  - lstm_persist: 128 persistent blocks x 256 thr. Block owns n0..n0+7 of H
//    => gate cols {i,f,g,o} x 8 (32 cols). W_hh/W_ih slices live in VGPR
//    B-fragments (bf16), loaded once. h double-buffered bf16 in ws. Per-step
//    global barrier (central counter + sense flag, agent atomics + fences).
//    xp(t+1) MFMA prefetched between barrier arrive and poll.

#define B_  64
#define S_  512
#define D_  544
#define H_  1024
#define GB  128   // persistent blocks
#define NC  8     // h-columns per block = H_/GB

typedef __attribute__((ext_vector_type(8))) short bf16x8;
typedef __attribute__((ext_vector_type(4))) float f32x4;

__device__ inline ushort f2b(float x){
  unsigned u = __float_as_uint(x);
  u = (u + 0x7FFFu + ((u >> 16) & 1u)) >> 16;   // RNE
  return (ushort)u;
}

__device__ inline bf16x8 pack8(float4 a, float4 b){
  bf16x8 r;
  r[0]=(short)f2b(a.x); r[1]=(short)f2b(a.y); r[2]=(short)f2b(a.z); r[3]=(short)f2b(a.w);
  r[4]=(short)f2b(b.x); r[5]=(short)f2b(b.y); r[6]=(short)f2b(b.z); r[7]=(short)f2b(b.w);
  return r;
}

__device__ inline float sigm(float x){ return __builtin_amdgcn_rcpf(1.f + __expf(-x)); }
__device__ inline float tanh_(float x){ return 1.f - 2.f*__builtin_amdgcn_rcpf(1.f + __expf(2.f*x)); }

__global__ void cvt_x(const float* __restrict__ x, ushort* __restrict__ xb, int n4){
  int i = blockIdx.x*256 + threadIdx.x;
  if (i >= n4) return;
  float4 v = ((const float4*)x)[i];
  ushort4 o;
  o.x=f2b(v.x); o.y=f2b(v.y); o.z=f2b(v.z); o.w=f2b(v.w);
  ((ushort4*)xb)[i] = o;
}

__global__ __launch_bounds__(256,1) void lstm_persist(
    const float* __restrict__ Wih, const float* __restrict__ Whh,
    const float* __restrict__ bih, const float* __restrict__ bhh,
    const ushort* __restrict__ Xb,
    ushort* hbuf,          // 2 x [64][1024] bf16 (double buffer), pre-zeroed
    unsigned* bar,         // [0]=monotonic count, [1]=sense, pre-zeroed
    float* __restrict__ out)
{
  const int tid  = threadIdx.x;
  const int wave = tid >> 6;          // K-quarter
  const int lane = tid & 63;
  const int c16  = lane & 15;
  const int quad = lane >> 4;
  const int n0   = blockIdx.x * NC;

  __shared__ float gates[4][64][33];  // [wave][m][gatecol], padded

  // tile0 cols 0..7 = gate i, 8..15 = gate f; tile1: g, o.
  const int u8 = c16 & 7;
  const int j0 = ((c16>>3)    )*H_ + n0 + u8;   // W row for tile0 col c16
  const int j1 = ((c16>>3) + 2)*H_ + n0 + u8;   // W row for tile1 col c16

  // ---- W_hh fragments: this wave covers K in [wave*256, wave*256+256) ----
  bf16x8 whhf[2][8];
  #pragma unroll
  for (int i = 0; i < 8; ++i){
    int k = wave*256 + i*32 + quad*8;
    const float4* p0 = (const float4*)(Whh + j0*H_ + k);
    const float4* p1 = (const float4*)(Whh + j1*H_ + k);
    whhf[0][i] = pack8(p0[0], p0[1]);
    whhf[1][i] = pack8(p1[0], p1[1]);
  }
  // ---- W_ih fragments: K-iters it = wave, wave+4, ... < 17 ----
  bf16x8 wihf[2][5];
  #pragma unroll
  for (int ii = 0; ii < 5; ++ii){
    int it = wave + 4*ii;
    if (it < 17){
      int k = it*32 + quad*8;
      const float4* p0 = (const float4*)(Wih + j0*D_ + k);
      const float4* p1 = (const float4*)(Wih + j1*D_ + k);
      wihf[0][ii] = pack8(p0[0], p0[1]);
      wihf[1][ii] = pack8(p1[0], p1[1]);
    }
  }

  // ---- bias (per update-thread column u = tid&7) ----
  float bsum[4];
  {
    int u = tid & 7;
    #pragma unroll
    for (int g = 0; g < 4; ++g) bsum[g] = bih[g*H_ + n0 + u] + bhh[g*H_ + n0 + u];
  }

  float cst[2] = {0.f, 0.f};   // c state: (m = tid>>3, u) and (m+32, u)
  f32x4 accx[4][2];            // xp accumulators (prefetched)

  auto xp_gemm = [&](int t){
    #pragma unroll
    for (int ii = 0; ii < 5; ++ii){
      int it = wave + 4*ii;
      if (it < 17){
        int k = it*32 + quad*8;
        bf16x8 a[4];
        #pragma unroll
        for (int rt = 0; rt < 4; ++rt){
          int b = rt*16 + c16;
          a[rt] = *(const bf16x8*)(Xb + (b*S_ + t)*D_ + k);
        }
        #pragma unroll
        for (int rt = 0; rt < 4; ++rt){
          accx[rt][0] = __builtin_amdgcn_mfma_f32_16x16x32_bf16(a[rt], wihf[0][ii], accx[rt][0], 0,0,0);
          accx[rt][1] = __builtin_amdgcn_mfma_f32_16x16x32_bf16(a[rt], wihf[1][ii], accx[rt][1], 0,0,0);
        }
      }
    }
  };

  // prefetch xp for t=0
  #pragma unroll
  for (int rt = 0; rt < 4; ++rt){
    accx[rt][0] = (f32x4){0.f,0.f,0.f,0.f};
    accx[rt][1] = (f32x4){0.f,0.f,0.f,0.f};
  }
  xp_gemm(0);

  for (int t = 0; t < S_; ++t){
    const ushort* hprev = hbuf + (t & 1) * (B_*H_);
    ushort*       hnext = hbuf + ((t & 1) ^ 1) * (B_*H_);

    // ---- recurrent GEMM: gates += h(t-1) . W_hh^T (this wave's K-quarter) ----
    f32x4 acch[4][2];
    #pragma unroll
    for (int rt = 0; rt < 4; ++rt){
      acch[rt][0] = (f32x4){0.f,0.f,0.f,0.f};
      acch[rt][1] = (f32x4){0.f,0.f,0.f,0.f};
    }
    #pragma unroll
    for (int i = 0; i < 8; ++i){
      int k = wave*256 + i*32 + quad*8;
      bf16x8 a[4];
      #pragma unroll
      for (int rt = 0; rt < 4; ++rt)
        a[rt] = *(const bf16x8*)(hprev + (rt*16 + c16)*H_ + k);
      #pragma unroll
      for (int rt = 0; rt < 4; ++rt){
        acch[rt][0] = __builtin_amdgcn_mfma_f32_16x16x32_bf16(a[rt], whhf[0][i], acch[rt][0], 0,0,0);
        acch[rt][1] = __builtin_amdgcn_mfma_f32_16x16x32_bf16(a[rt], whhf[1][i], acch[rt][1], 0,0,0);
      }
    }

    // ---- write per-wave partial gate sums (hh + xp) to LDS ----
    #pragma unroll
    for (int rt = 0; rt < 4; ++rt)
      #pragma unroll
      for (int tt = 0; tt < 2; ++tt)
        #pragma unroll
        for (int r = 0; r < 4; ++r)
          gates[wave][rt*16 + quad*4 + r][tt*16 + c16] = acch[rt][tt][r] + accx[rt][tt][r];
    __syncthreads();

    // ---- nonlinearity + state update (512 (m,u) pairs / 256 threads) ----
    #pragma unroll
    for (int pp = 0; pp < 2; ++pp){
      int m = (tid + pp*256) >> 3;
      int u = tid & 7;
      float gi = bsum[0], gf = bsum[1], gg = bsum[2], go = bsum[3];
      #pragma unroll
      for (int q = 0; q < 4; ++q){
        gi += gates[q][m][u];
        gf += gates[q][m][8+u];
        gg += gates[q][m][16+u];
        go += gates[q][m][24+u];
      }
      float iv = sigm(gi), fv = sigm(gf), gv = tanh_(gg), ov = sigm(go);
      float cn = fv*cst[pp] + iv*gv;
      cst[pp] = cn;
      float hn = ov*tanh_(cn);
      hnext[m*H_ + n0 + u] = f2b(hn);
      if (t == S_-1){
        out[m*H_ + n0 + u]           = hn;   // h_n
        out[B_*H_ + m*H_ + n0 + u]   = cn;   // c_n
      }
    }

    if (t < S_-1){
      // release h(t) writes, then arrive
      __builtin_amdgcn_fence(__ATOMIC_RELEASE, "agent");
      __syncthreads();
      if (tid == 0){
        unsigned old = __hip_atomic_fetch_add(&bar[0], 1u, __ATOMIC_ACQ_REL, __HIP_MEMORY_SCOPE_AGENT);
        if (old == (unsigned)(t+1)*GB - 1u)
          __hip_atomic_store(&bar[1], (unsigned)(t+1), __ATOMIC_RELEASE, __HIP_MEMORY_SCOPE_AGENT);
      }
      // prefetch xp(t+1) while others arrive
      #pragma unroll
      for (int rt = 0; rt < 4; ++rt){
        accx[rt][0] = (f32x4){0.f,0.f,0.f,0.f};
        accx[rt][1] = (f32x4){0.f,0.f,0.f,0.f};
      }
      xp_gemm(t+1);
      if (tid == 0){
        long guard = 0;
        while (__hip_atomic_load(&bar[1], __ATOMIC_ACQUIRE, __HIP_MEMORY_SCOPE_AGENT) < (unsigned)(t+1)){
          __builtin_amdgcn_s_sleep(1);
          if (++guard > (1L<<24)) break;   // safety: never hang the harness
        }
      }
      __syncthreads();
      __builtin_amdgcn_fence(__ATOMIC_ACQUIRE, "agent");
    }
  }
}

extern "C" void kernel_launch(void* const* d_in, const int* in_sizes, int n_in,
                              void* d_out, int out_size, void* d_ws, size_t ws_size,
                              hipStream_t stream) {
  const float* X   = (const float*)d_in[0];
  const float* Wih = (const float*)d_in[1];
  const float* Whh = (const float*)d_in[2];
  const float* bih = (const float*)d_in[3];
  const float* bhh = (const float*)d_in[4];
  float* out = (float*)d_out;

  // ws layout: [0, 256KB) h double buffer (bf16), [256KB,+128B) barrier,
  //            [512KB, +35.7MB) X in bf16.
  char* ws = (char*)d_ws;
  const size_t HBUF_BYTES = 2ull * B_ * H_ * sizeof(ushort);   // 262144
  const size_t XB_OFF     = 524288;
  const size_t XB_BYTES   = (size_t)B_ * S_ * D_ * sizeof(ushort);  // 35.65 MB
  if (ws_size < XB_OFF + XB_BYTES) return;  // insufficient scratch: fail visibly

  ushort*   hbuf = (ushort*)ws;
  unsigned* bar  = (unsigned*)(ws + HBUF_BYTES);
  ushort*   Xb   = (ushort*)(ws + XB_OFF);

  hipMemsetAsync(d_ws, 0, XB_OFF, stream);   // zero h0 + barrier

  int n4 = B_*S_*D_/4;
  cvt_x<<<(n4 + 255)/256, 256, 0, stream>>>(X, Xb, n4);
  lstm_persist<<<GB, 256, 0, stream>>>(Wih, Whh, bih, bhh, Xb, hbuf, bar, out);
}

// Round 2
// 7121.535 us; speedup vs baseline: 1.6433x; 1.6433x over previous
//
#include <hip/hip_runtime.h>
#include <hip/hip_bf16.h>

// PBRNN LSTM: B=64, S=512, D=544, H=1024. out = [h_n; c_n] fp32 [2,64,1024].
//
// Round 2: latency-focused rework of the per-step coherence path.
//  - h exchange: agent-scope relaxed atomic loads/stores (sc0 sc1 per-op
//    coherence) -> NO buffer_wbl2/buffer_inv on the critical path, X stays
//    warm in L2.
//  - barrier: distributed flag array flags[128] (monotonic step tags),
//    arrive = 1 coherent store after explicit vmcnt(0) drain, depart =
//    128-thread parallel poll + __syncthreads_and. No serialized RMWs.
//  - gates LDS layout [4][32][67]: write <=2-way, read 2-way (free).

#define B_  64
#define S_  512
#define D_  544
#define H_  1024
#define GB  128   // persistent blocks
#define NC  8     // h-columns per block = H_/GB

typedef __attribute__((ext_vector_type(8))) short bf16x8;
typedef __attribute__((ext_vector_type(4))) float f32x4;

__device__ inline ushort f2b(float x){
  unsigned u = __float_as_uint(x);
  u = (u + 0x7FFFu + ((u >> 16) & 1u)) >> 16;   // RNE
  return (ushort)u;
}

__device__ inline bf16x8 pack8(float4 a, float4 b){
  bf16x8 r;
  r[0]=(short)f2b(a.x); r[1]=(short)f2b(a.y); r[2]=(short)f2b(a.z); r[3]=(short)f2b(a.w);
  r[4]=(short)f2b(b.x); r[5]=(short)f2b(b.y); r[6]=(short)f2b(b.z); r[7]=(short)f2b(b.w);
  return r;
}

// agent-coherent 16B h-fragment load (2 x b64 relaxed atomic -> sc0 sc1)
__device__ inline bf16x8 ldh8(const ushort* p){
  union { unsigned long long u[2]; bf16x8 v; } r;
  const unsigned long long* q = (const unsigned long long*)p;
  r.u[0] = __hip_atomic_load(q,     __ATOMIC_RELAXED, __HIP_MEMORY_SCOPE_AGENT);
  r.u[1] = __hip_atomic_load(q + 1, __ATOMIC_RELAXED, __HIP_MEMORY_SCOPE_AGENT);
  return r.v;
}

__device__ inline float sigm(float x){ return __builtin_amdgcn_rcpf(1.f + __expf(-x)); }
__device__ inline float tanh_(float x){ return 1.f - 2.f*__builtin_amdgcn_rcpf(1.f + __expf(2.f*x)); }

__global__ void cvt_x(const float* __restrict__ x, ushort* __restrict__ xb, int n4){
  int i = blockIdx.x*256 + threadIdx.x;
  if (i >= n4) return;
  float4 v = ((const float4*)x)[i];
  ushort4 o;
  o.x=f2b(v.x); o.y=f2b(v.y); o.z=f2b(v.z); o.w=f2b(v.w);
  ((ushort4*)xb)[i] = o;
}

__global__ __launch_bounds__(256,1) void lstm_persist(
    const float* __restrict__ Wih, const float* __restrict__ Whh,
    const float* __restrict__ bih, const float* __restrict__ bhh,
    const ushort* __restrict__ Xb,
    ushort* hbuf,          // 2 x [64][1024] bf16 (double buffer), pre-zeroed
    unsigned* flags,       // [GB] monotonic step tags, pre-zeroed
    float* __restrict__ out)
{
  const int tid  = threadIdx.x;
  const int wave = tid >> 6;          // K-quarter
  const int lane = tid & 63;
  const int c16  = lane & 15;
  const int quad = lane >> 4;
  const int n0   = blockIdx.x * NC;

  // [wave][gatecol 0..31][m 0..63] padded to 67: write <=2-way, read 2-way.
  __shared__ float gates[4][32][67];

  // tile0 cols 0..7 = gate i, 8..15 = gate f; tile1: g, o.
  const int u8 = c16 & 7;
  const int j0 = ((c16>>3)    )*H_ + n0 + u8;   // W row for tile0 col c16
  const int j1 = ((c16>>3) + 2)*H_ + n0 + u8;   // W row for tile1 col c16

  // ---- W_hh fragments: this wave covers K in [wave*256, wave*256+256) ----
  bf16x8 whhf[2][8];
  #pragma unroll
  for (int i = 0; i < 8; ++i){
    int k = wave*256 + i*32 + quad*8;
    const float4* p0 = (const float4*)(Whh + j0*H_ + k);
    const float4* p1 = (const float4*)(Whh + j1*H_ + k);
    whhf[0][i] = pack8(p0[0], p0[1]);
    whhf[1][i] = pack8(p1[0], p1[1]);
  }
  // ---- W_ih fragments: K-iters it = wave, wave+4, ... < 17 ----
  bf16x8 wihf[2][5];
  #pragma unroll
  for (int ii = 0; ii < 5; ++ii){
    int it = wave + 4*ii;
    if (it < 17){
      int k = it*32 + quad*8;
      const float4* p0 = (const float4*)(Wih + j0*D_ + k);
      const float4* p1 = (const float4*)(Wih + j1*D_ + k);
      wihf[0][ii] = pack8(p0[0], p0[1]);
      wihf[1][ii] = pack8(p1[0], p1[1]);
    }
  }

  // ---- update-thread mapping: m = tid&63, u = (tid>>6)*2 + pp ----
  const int m_u  = tid & 63;
  const int u0   = (tid >> 6) * 2;
  float bsum2[2][4];
  #pragma unroll
  for (int pp = 0; pp < 2; ++pp)
    #pragma unroll
    for (int g = 0; g < 4; ++g)
      bsum2[pp][g] = bih[g*H_ + n0 + u0 + pp] + bhh[g*H_ + n0 + u0 + pp];

  float cst[2] = {0.f, 0.f};   // c state for (m_u, u0) and (m_u, u0+1)
  f32x4 accx[4][2];            // xp accumulators (prefetched)

  auto xp_gemm = [&](int t){
    #pragma unroll
    for (int ii = 0; ii < 5; ++ii){
      int it = wave + 4*ii;
      if (it < 17){
        int k = it*32 + quad*8;
        bf16x8 a[4];
        #pragma unroll
        for (int rt = 0; rt < 4; ++rt){
          int b = rt*16 + c16;
          a[rt] = *(const bf16x8*)(Xb + (b*S_ + t)*D_ + k);
        }
        #pragma unroll
        for (int rt = 0; rt < 4; ++rt){
          accx[rt][0] = __builtin_amdgcn_mfma_f32_16x16x32_bf16(a[rt], wihf[0][ii], accx[rt][0], 0,0,0);
          accx[rt][1] = __builtin_amdgcn_mfma_f32_16x16x32_bf16(a[rt], wihf[1][ii], accx[rt][1], 0,0,0);
        }
      }
    }
  };

  // prefetch xp for t=0
  #pragma unroll
  for (int rt = 0; rt < 4; ++rt){
    accx[rt][0] = (f32x4){0.f,0.f,0.f,0.f};
    accx[rt][1] = (f32x4){0.f,0.f,0.f,0.f};
  }
  xp_gemm(0);

  for (int t = 0; t < S_; ++t){
    const ushort* hprev = hbuf + (t & 1) * (B_*H_);
    ushort*       hnext = hbuf + ((t & 1) ^ 1) * (B_*H_);

    // ---- recurrent GEMM: gates += h(t-1) . W_hh^T (this wave's K-quarter) ----
    f32x4 acch[4][2];
    #pragma unroll
    for (int rt = 0; rt < 4; ++rt){
      acch[rt][0] = (f32x4){0.f,0.f,0.f,0.f};
      acch[rt][1] = (f32x4){0.f,0.f,0.f,0.f};
    }
    #pragma unroll
    for (int i = 0; i < 8; ++i){
      int k = wave*256 + i*32 + quad*8;
      bf16x8 a[4];
      #pragma unroll
      for (int rt = 0; rt < 4; ++rt)
        a[rt] = ldh8(hprev + (rt*16 + c16)*H_ + k);
      #pragma unroll
      for (int rt = 0; rt < 4; ++rt){
        acch[rt][0] = __builtin_amdgcn_mfma_f32_16x16x32_bf16(a[rt], whhf[0][i], acch[rt][0], 0,0,0);
        acch[rt][1] = __builtin_amdgcn_mfma_f32_16x16x32_bf16(a[rt], whhf[1][i], acch[rt][1], 0,0,0);
      }
    }

    // ---- write per-wave partial gate sums (hh + xp) to LDS ----
    #pragma unroll
    for (int rt = 0; rt < 4; ++rt)
      #pragma unroll
      for (int tt = 0; tt < 2; ++tt)
        #pragma unroll
        for (int r = 0; r < 4; ++r)
          gates[wave][tt*16 + c16][rt*16 + quad*4 + r] = acch[rt][tt][r] + accx[rt][tt][r];
    __syncthreads();

    // ---- nonlinearity + state update: thread owns (m_u, u0) & (m_u, u0+1) ----
    {
      float hn2[2], cn2[2];
      #pragma unroll
      for (int pp = 0; pp < 2; ++pp){
        int u = u0 + pp;
        float gi = bsum2[pp][0], gf = bsum2[pp][1], gg = bsum2[pp][2], go = bsum2[pp][3];
        #pragma unroll
        for (int q = 0; q < 4; ++q){
          gi += gates[q][u     ][m_u];
          gf += gates[q][8  + u][m_u];
          gg += gates[q][16 + u][m_u];
          go += gates[q][24 + u][m_u];
        }
        float iv = sigm(gi), fv = sigm(gf), gv = tanh_(gg), ov = sigm(go);
        float cn = fv*cst[pp] + iv*gv;
        cst[pp] = cn;
        cn2[pp] = cn;
        hn2[pp] = ov*tanh_(cn);
      }
      // packed coherent 4B store of two adjacent bf16 h values
      unsigned pk = (unsigned)f2b(hn2[0]) | ((unsigned)f2b(hn2[1]) << 16);
      __hip_atomic_store((unsigned*)(hnext + m_u*H_ + n0 + u0), pk,
                         __ATOMIC_RELAXED, __HIP_MEMORY_SCOPE_AGENT);
      if (t == S_-1){
        #pragma unroll
        for (int pp = 0; pp < 2; ++pp){
          out[m_u*H_ + n0 + u0 + pp]          = hn2[pp];   // h_n
          out[B_*H_ + m_u*H_ + n0 + u0 + pp]  = cn2[pp];   // c_n
        }
      }
    }

    if (t < S_-1){
      // drain own h stores to the coherence point, then block-wide barrier
      asm volatile("s_waitcnt vmcnt(0)" ::: "memory");
      __syncthreads();
      if (tid == 0)
        __hip_atomic_store(&flags[blockIdx.x], (unsigned)(t+1),
                           __ATOMIC_RELAXED, __HIP_MEMORY_SCOPE_AGENT);
      // prefetch xp(t+1) while other blocks finish
      #pragma unroll
      for (int rt = 0; rt < 4; ++rt){
        accx[rt][0] = (f32x4){0.f,0.f,0.f,0.f};
        accx[rt][1] = (f32x4){0.f,0.f,0.f,0.f};
      }
      xp_gemm(t+1);
      // parallel poll: all GB flags must reach t+1
      {
        const unsigned target = (unsigned)(t+1);
        long guard = 0;
        for (;;){
          unsigned v = target;
          if (tid < GB)
            v = __hip_atomic_load(&flags[tid], __ATOMIC_RELAXED, __HIP_MEMORY_SCOPE_AGENT);
          if (__syncthreads_and((int)(v >= target))) break;
          if (++guard > (1L<<21)) break;   // safety: never hang the harness
        }
      }
    }
  }
}

extern "C" void kernel_launch(void* const* d_in, const int* in_sizes, int n_in,
                              void* d_out, int out_size, void* d_ws, size_t ws_size,
                              hipStream_t stream) {
  const float* X   = (const float*)d_in[0];
  const float* Wih = (const float*)d_in[1];
  const float* Whh = (const float*)d_in[2];
  const float* bih = (const float*)d_in[3];
  const float* bhh = (const float*)d_in[4];
  float* out = (float*)d_out;

  // ws layout: [0, 256KB) h double buffer (bf16), [256KB, +512B) flags,
  //            [512KB, +35.7MB) X in bf16.
  char* ws = (char*)d_ws;
  const size_t HBUF_BYTES = 2ull * B_ * H_ * sizeof(ushort);   // 262144
  const size_t XB_OFF     = 524288;
  const size_t XB_BYTES   = (size_t)B_ * S_ * D_ * sizeof(ushort);  // 35.65 MB
  if (ws_size < XB_OFF + XB_BYTES) return;  // insufficient scratch: fail visibly

  ushort*   hbuf  = (ushort*)ws;
  unsigned* flags = (unsigned*)(ws + HBUF_BYTES);
  ushort*   Xb    = (ushort*)(ws + XB_OFF);

  hipMemsetAsync(d_ws, 0, XB_OFF, stream);   // zero h0 + flags

  int n4 = B_*S_*D_/4;
  cvt_x<<<(n4 + 255)/256, 256, 0, stream>>>(X, Xb, n4);
  lstm_persist<<<GB, 256, 0, stream>>>(Wih, Whh, bih, bhh, Xb, hbuf, flags, out);
}

// Round 3
// 5139.775 us; speedup vs baseline: 2.2769x; 1.3856x over previous
//
#include <hip/hip_runtime.h>
#include <hip/hip_bf16.h>

// PBRNN LSTM: B=64, S=512, D=544, H=1024. out = [h_n; c_n] fp32 [2,64,1024].
//
// Round 3: coalesce the h exchange.
//  - Swapped MFMA operands: A = W (M = 32 gate cols / block), B = h
//    (N = 64 batches). Output D is [gatecol][batch].
//  - Blocked h layout hbuf[2][GB][64][8] (bf16): each block's h slab is one
//    contiguous 1KB region -> h stores fully coalesced (256 x consecutive
//    4B), h B-fragment loads fully coalesced (consecutive lanes read
//    consecutive 16B).
//  - Barrier: per-thread spin on its own flag + one __syncthreads (no
//    repeated __syncthreads_and).

#define B_  64
#define S_  512
#define D_  544
#define H_  1024
#define GB  128   // persistent blocks
#define NC  8     // h-columns per block = H_/GB

typedef __attribute__((ext_vector_type(8))) short bf16x8;
typedef __attribute__((ext_vector_type(4))) float f32x4;

__device__ inline ushort f2b(float x){
  unsigned u = __float_as_uint(x);
  u = (u + 0x7FFFu + ((u >> 16) & 1u)) >> 16;   // RNE
  return (ushort)u;
}

__device__ inline bf16x8 pack8(float4 a, float4 b){
  bf16x8 r;
  r[0]=(short)f2b(a.x); r[1]=(short)f2b(a.y); r[2]=(short)f2b(a.z); r[3]=(short)f2b(a.w);
  r[4]=(short)f2b(b.x); r[5]=(short)f2b(b.y); r[6]=(short)f2b(b.z); r[7]=(short)f2b(b.w);
  return r;
}

// agent-coherent 16B h-fragment load (2 x b64 relaxed atomic)
__device__ inline bf16x8 ldh8(const ushort* p){
  union { unsigned long long u[2]; bf16x8 v; } r;
  const unsigned long long* q = (const unsigned long long*)p;
  r.u[0] = __hip_atomic_load(q,     __ATOMIC_RELAXED, __HIP_MEMORY_SCOPE_AGENT);
  r.u[1] = __hip_atomic_load(q + 1, __ATOMIC_RELAXED, __HIP_MEMORY_SCOPE_AGENT);
  return r.v;
}

__device__ inline float sigm(float x){ return __builtin_amdgcn_rcpf(1.f + __expf(-x)); }
__device__ inline float tanh_(float x){ return 1.f - 2.f*__builtin_amdgcn_rcpf(1.f + __expf(2.f*x)); }

__global__ void cvt_x(const float* __restrict__ x, ushort* __restrict__ xb, int n4){
  int i = blockIdx.x*256 + threadIdx.x;
  if (i >= n4) return;
  float4 v = ((const float4*)x)[i];
  ushort4 o;
  o.x=f2b(v.x); o.y=f2b(v.y); o.z=f2b(v.z); o.w=f2b(v.w);
  ((ushort4*)xb)[i] = o;
}

__global__ __launch_bounds__(256,1) void lstm_persist(
    const float* __restrict__ Wih, const float* __restrict__ Whh,
    const float* __restrict__ bih, const float* __restrict__ bhh,
    const ushort* __restrict__ Xb,
    ushort* hbuf,          // [2][GB][64][8] bf16 blocked double buffer, pre-zeroed
    unsigned* flags,       // [GB] monotonic step tags, pre-zeroed
    float* __restrict__ out)
{
  const int tid  = threadIdx.x;
  const int wave = tid >> 6;          // K-quarter
  const int lane = tid & 63;
  const int c16  = lane & 15;
  const int quad = lane >> 4;
  const int n0   = blockIdx.x * NC;

  // [wave][gatecol 0..31][batch 0..63] padded to 67.
  __shared__ float gates[4][32][67];

  // M-tiles of gate cols: tt=0 -> gates i,f ; tt=1 -> gates g,o.
  const int u8 = c16 & 7;
  const int j0 = ((c16>>3)    )*H_ + n0 + u8;   // W row for tile0 lane-col
  const int j1 = ((c16>>3) + 2)*H_ + n0 + u8;   // W row for tile1 lane-col

  // ---- W_hh A-fragments: this wave covers K in [wave*256, wave*256+256) ----
  bf16x8 whhf[2][8];
  #pragma unroll
  for (int i = 0; i < 8; ++i){
    int k = wave*256 + i*32 + quad*8;
    const float4* p0 = (const float4*)(Whh + j0*H_ + k);
    const float4* p1 = (const float4*)(Whh + j1*H_ + k);
    whhf[0][i] = pack8(p0[0], p0[1]);
    whhf[1][i] = pack8(p1[0], p1[1]);
  }
  // ---- W_ih A-fragments: K-iters it = wave, wave+4, ... < 17 ----
  bf16x8 wihf[2][5];
  #pragma unroll
  for (int ii = 0; ii < 5; ++ii){
    int it = wave + 4*ii;
    if (it < 17){
      int k = it*32 + quad*8;
      const float4* p0 = (const float4*)(Wih + j0*D_ + k);
      const float4* p1 = (const float4*)(Wih + j1*D_ + k);
      wihf[0][ii] = pack8(p0[0], p0[1]);
      wihf[1][ii] = pack8(p1[0], p1[1]);
    }
  }

  // ---- update-thread mapping: batch = tid>>2, u pair = 2*(tid&3)+{0,1} ----
  const int mb  = tid >> 2;
  const int u2  = tid & 3;
  float bsum2[2][4];
  #pragma unroll
  for (int pp = 0; pp < 2; ++pp)
    #pragma unroll
    for (int g = 0; g < 4; ++g)
      bsum2[pp][g] = bih[g*H_ + n0 + 2*u2 + pp] + bhh[g*H_ + n0 + 2*u2 + pp];

  float cst[2] = {0.f, 0.f};
  f32x4 accx[4][2];            // [batch-tile rt][gate-tile tt]

  auto xp_gemm = [&](int t){
    #pragma unroll
    for (int ii = 0; ii < 5; ++ii){
      int it = wave + 4*ii;
      if (it < 17){
        int k = it*32 + quad*8;
        bf16x8 b[4];
        #pragma unroll
        for (int rt = 0; rt < 4; ++rt){
          int batch = rt*16 + c16;
          b[rt] = *(const bf16x8*)(Xb + (batch*S_ + t)*D_ + k);
        }
        #pragma unroll
        for (int rt = 0; rt < 4; ++rt){
          accx[rt][0] = __builtin_amdgcn_mfma_f32_16x16x32_bf16(wihf[0][ii], b[rt], accx[rt][0], 0,0,0);
          accx[rt][1] = __builtin_amdgcn_mfma_f32_16x16x32_bf16(wihf[1][ii], b[rt], accx[rt][1], 0,0,0);
        }
      }
    }
  };

  #pragma unroll
  for (int rt = 0; rt < 4; ++rt){
    accx[rt][0] = (f32x4){0.f,0.f,0.f,0.f};
    accx[rt][1] = (f32x4){0.f,0.f,0.f,0.f};
  }
  xp_gemm(0);

  for (int t = 0; t < S_; ++t){
    const ushort* hprev = hbuf + (t & 1) * (B_*H_);
    ushort*       hnext = hbuf + ((t & 1) ^ 1) * (B_*H_);

    // ---- recurrent GEMM: gates^T += W_hh . h(t-1)^T (this wave's K-quarter)
    // h blocked: slab kb = k_global/8 at hprev[kb*512 + batch*8]
    f32x4 acch[4][2];
    #pragma unroll
    for (int rt = 0; rt < 4; ++rt){
      acch[rt][0] = (f32x4){0.f,0.f,0.f,0.f};
      acch[rt][1] = (f32x4){0.f,0.f,0.f,0.f};
    }
    #pragma unroll
    for (int i = 0; i < 8; ++i){
      const int kb = wave*32 + i*4 + quad;     // owning block of these 8 k
      bf16x8 b[4];
      #pragma unroll
      for (int rt = 0; rt < 4; ++rt)
        b[rt] = ldh8(hprev + kb*512 + (rt*16 + c16)*8);
      #pragma unroll
      for (int rt = 0; rt < 4; ++rt){
        acch[rt][0] = __builtin_amdgcn_mfma_f32_16x16x32_bf16(whhf[0][i], b[rt], acch[rt][0], 0,0,0);
        acch[rt][1] = __builtin_amdgcn_mfma_f32_16x16x32_bf16(whhf[1][i], b[rt], acch[rt][1], 0,0,0);
      }
    }

    // ---- write per-wave partial gate sums (hh + xp) to LDS ----
    // D layout: batch = c16 (+16*rt), gatecol = tt*16 + quad*4 + r
    #pragma unroll
    for (int rt = 0; rt < 4; ++rt)
      #pragma unroll
      for (int tt = 0; tt < 2; ++tt)
        #pragma unroll
        for (int r = 0; r < 4; ++r)
          gates[wave][tt*16 + quad*4 + r][rt*16 + c16] = acch[rt][tt][r] + accx[rt][tt][r];
    __syncthreads();

    // ---- nonlinearity + state update: thread owns (mb, 2*u2) & (mb, 2*u2+1) ----
    {
      float hn2[2], cn2[2];
      #pragma unroll
      for (int pp = 0; pp < 2; ++pp){
        int u = 2*u2 + pp;
        float gi = bsum2[pp][0], gf = bsum2[pp][1], gg = bsum2[pp][2], go = bsum2[pp][3];
        #pragma unroll
        for (int q = 0; q < 4; ++q){
          gi += gates[q][     u][mb];
          gf += gates[q][ 8 + u][mb];
          gg += gates[q][16 + u][mb];
          go += gates[q][24 + u][mb];
        }
        float iv = sigm(gi), fv = sigm(gf), gv = tanh_(gg), ov = sigm(go);
        float cn = fv*cst[pp] + iv*gv;
        cst[pp] = cn;
        cn2[pp] = cn;
        hn2[pp] = ov*tanh_(cn);
      }
      // coalesced: thread tid stores 4B at slab offset 2*tid (ushorts)
      unsigned pk = (unsigned)f2b(hn2[0]) | ((unsigned)f2b(hn2[1]) << 16);
      __hip_atomic_store((unsigned*)(hnext + (size_t)blockIdx.x*512 + mb*8 + 2*u2), pk,
                         __ATOMIC_RELAXED, __HIP_MEMORY_SCOPE_AGENT);
      if (t == S_-1){
        #pragma unroll
        for (int pp = 0; pp < 2; ++pp){
          out[mb*H_ + n0 + 2*u2 + pp]          = hn2[pp];   // h_n
          out[B_*H_ + mb*H_ + n0 + 2*u2 + pp]  = cn2[pp];   // c_n
        }
      }
    }

    if (t < S_-1){
      // drain own h stores to the coherence point, then arrive
      asm volatile("s_waitcnt vmcnt(0)" ::: "memory");
      __syncthreads();
      if (tid == 0)
        __hip_atomic_store(&flags[blockIdx.x], (unsigned)(t+1),
                           __ATOMIC_RELAXED, __HIP_MEMORY_SCOPE_AGENT);
      // prefetch xp(t+1) while other blocks finish
      #pragma unroll
      for (int rt = 0; rt < 4; ++rt){
        accx[rt][0] = (f32x4){0.f,0.f,0.f,0.f};
        accx[rt][1] = (f32x4){0.f,0.f,0.f,0.f};
      }
      xp_gemm(t+1);
      // per-thread spin on own flag, then one block barrier
      {
        const unsigned target = (unsigned)(t+1);
        if (tid < GB){
          long guard = 0;
          while (__hip_atomic_load(&flags[tid], __ATOMIC_RELAXED, __HIP_MEMORY_SCOPE_AGENT) < target){
            if (++guard > (1L<<22)) break;   // safety: never hang the harness
          }
        }
        __syncthreads();
      }
    }
  }
}

extern "C" void kernel_launch(void* const* d_in, const int* in_sizes, int n_in,
                              void* d_out, int out_size, void* d_ws, size_t ws_size,
                              hipStream_t stream) {
  const float* X   = (const float*)d_in[0];
  const float* Wih = (const float*)d_in[1];
  const float* Whh = (const float*)d_in[2];
  const float* bih = (const float*)d_in[3];
  const float* bhh = (const float*)d_in[4];
  float* out = (float*)d_out;

  // ws layout: [0, 256KB) h double buffer (bf16, blocked), [256KB, +512B) flags,
  //            [512KB, +35.7MB) X in bf16.
  char* ws = (char*)d_ws;
  const size_t HBUF_BYTES = 2ull * B_ * H_ * sizeof(ushort);   // 262144
  const size_t XB_OFF     = 524288;
  const size_t XB_BYTES   = (size_t)B_ * S_ * D_ * sizeof(ushort);  // 35.65 MB
  if (ws_size < XB_OFF + XB_BYTES) return;  // insufficient scratch: fail visibly

  ushort*   hbuf  = (ushort*)ws;
  unsigned* flags = (unsigned*)(ws + HBUF_BYTES);
  ushort*   Xb    = (ushort*)(ws + XB_OFF);

  hipMemsetAsync(d_ws, 0, XB_OFF, stream);   // zero h0 + flags

  int n4 = B_*S_*D_/4;
  cvt_x<<<(n4 + 255)/256, 256, 0, stream>>>(X, Xb, n4);
  lstm_persist<<<GB, 256, 0, stream>>>(Wih, Whh, bih, bhh, Xb, hbuf, flags, out);
}

// Round 4
// 2938.174 us; speedup vs baseline: 3.9830x; 1.7493x over previous
//
#include <hip/hip_runtime.h>
#include <hip/hip_bf16.h>

// PBRNN LSTM: B=64, S=512, D=544, H=1024. out = [h_n; c_n] fp32 [2,64,1024].
//
// Round 4: 2-D (col-group x batch-group) partitioning.
//  - 256 blocks = 64 cg x 4 bg, one per CU (VGPR>256 guarantees 1 block/CU).
//  - Block (cg,bg) owns h/c tile [16 batches][16 cols]; reads only its bg's
//    h slabs (32 KB/step, was 128 KB), writes one 512 B slab.
//  - W_hh slice (64 gate rows x 1024) and W_ih slice live fully in VGPRs.
//  - Barrier is per-bg (4 independent 64-block domains), s_sleep backoff.
//  - h slabs: hbuf[2][bg][cg][n16][k16] bf16 -> all loads/stores coalesced.

#define B_  64
#define S_  512
#define D_  544
#define H_  1024
#define CG_ 64
#define BG_ 4
#define GRID_ (CG_*BG_)

typedef __attribute__((ext_vector_type(8))) short bf16x8;
typedef __attribute__((ext_vector_type(4))) float f32x4;

__device__ inline ushort f2b(float x){
  unsigned u = __float_as_uint(x);
  u = (u + 0x7FFFu + ((u >> 16) & 1u)) >> 16;   // RNE
  return (ushort)u;
}

__device__ inline bf16x8 pack8(float4 a, float4 b){
  bf16x8 r;
  r[0]=(short)f2b(a.x); r[1]=(short)f2b(a.y); r[2]=(short)f2b(a.z); r[3]=(short)f2b(a.w);
  r[4]=(short)f2b(b.x); r[5]=(short)f2b(b.y); r[6]=(short)f2b(b.z); r[7]=(short)f2b(b.w);
  return r;
}

// agent-coherent 16B h-fragment load (2 x b64 relaxed atomic)
__device__ inline bf16x8 ldh8(const ushort* p){
  union { unsigned long long u[2]; bf16x8 v; } r;
  const unsigned long long* q = (const unsigned long long*)p;
  r.u[0] = __hip_atomic_load(q,     __ATOMIC_RELAXED, __HIP_MEMORY_SCOPE_AGENT);
  r.u[1] = __hip_atomic_load(q + 1, __ATOMIC_RELAXED, __HIP_MEMORY_SCOPE_AGENT);
  return r.v;
}

__device__ inline float sigm(float x){ return __builtin_amdgcn_rcpf(1.f + __expf(-x)); }
__device__ inline float tanh_(float x){ return 1.f - 2.f*__builtin_amdgcn_rcpf(1.f + __expf(2.f*x)); }

__global__ void cvt_x(const float* __restrict__ x, ushort* __restrict__ xb, int n4){
  int i = blockIdx.x*256 + threadIdx.x;
  if (i >= n4) return;
  float4 v = ((const float4*)x)[i];
  ushort4 o;
  o.x=f2b(v.x); o.y=f2b(v.y); o.z=f2b(v.z); o.w=f2b(v.w);
  ((ushort4*)xb)[i] = o;
}

__global__ __launch_bounds__(256,1) void lstm_persist(
    const float* __restrict__ Wih, const float* __restrict__ Whh,
    const float* __restrict__ bih, const float* __restrict__ bhh,
    const ushort* __restrict__ Xb,
    ushort* hbuf,          // [2][BG_][CG_][16][16] bf16 slabs, pre-zeroed
    unsigned* flags,       // [BG_*CG_] monotonic step tags, pre-zeroed
    float* __restrict__ out)
{
  const int tid  = threadIdx.x;
  const int wave = tid >> 6;          // K-quarter for W_hh
  const int lane = tid & 63;
  const int c16  = lane & 15;
  const int quad = lane >> 4;
  const int cg   = blockIdx.x & (CG_-1);
  const int bg   = blockIdx.x >> 6;

  // per-wave gate partials: [wave][gate-row 0..63][batch 0..15] padded
  __shared__ float gates_s[4][64][17];

  // ---- W_hh A-fragments (VGPR-pinned): 4 M-tiles (gates i,f,g,o) x 8 K-iters
  // M-tile mt row m=c16 -> global row mt*H_ + cg*16 + c16.
  bf16x8 whhf[4][8];
  #pragma unroll
  for (int mt = 0; mt < 4; ++mt){
    const size_t grow = (size_t)(mt*H_ + cg*16 + c16);
    #pragma unroll
    for (int i = 0; i < 8; ++i){
      int k = wave*256 + i*32 + quad*8;
      const float4* p = (const float4*)(Whh + grow*H_ + k);
      whhf[mt][i] = pack8(p[0], p[1]);
    }
  }
  // ---- W_ih A-fragments: K-iters it = wave, wave+4, ... < 17 ----
  bf16x8 wihf[4][5];
  #pragma unroll
  for (int mt = 0; mt < 4; ++mt){
    const size_t grow = (size_t)(mt*H_ + cg*16 + c16);
    #pragma unroll
    for (int ii = 0; ii < 5; ++ii){
      int it = wave + 4*ii;
      if (it < 17){
        int k = it*32 + quad*8;
        const float4* p = (const float4*)(Wih + grow*D_ + k);
        wihf[mt][ii] = pack8(p[0], p[1]);
      }
    }
  }

  // ---- update mapping: thread owns (batch nn, col uu); h addr = slab + tid ----
  const int uu = tid & 15;
  const int nn = tid >> 4;
  float bsum[4];
  #pragma unroll
  for (int g = 0; g < 4; ++g)
    bsum[g] = bih[g*H_ + cg*16 + uu] + bhh[g*H_ + cg*16 + uu];
  float cstate = 0.f;

  f32x4 acc[4];   // [gate tile]; holds xp(t), hh added on top

  auto zacc = [&]{
    #pragma unroll
    for (int mt = 0; mt < 4; ++mt) acc[mt] = (f32x4){0.f,0.f,0.f,0.f};
  };
  auto xp_gemm = [&](int t){
    #pragma unroll
    for (int ii = 0; ii < 5; ++ii){
      int it = wave + 4*ii;
      if (it < 17){
        int k = it*32 + quad*8;
        bf16x8 b = *(const bf16x8*)(Xb + ((size_t)(bg*16 + c16)*S_ + t)*D_ + k);
        #pragma unroll
        for (int mt = 0; mt < 4; ++mt)
          acc[mt] = __builtin_amdgcn_mfma_f32_16x16x32_bf16(wihf[mt][ii], b, acc[mt], 0,0,0);
      }
    }
  };

  zacc();
  xp_gemm(0);

  for (int t = 0; t < S_; ++t){
    const ushort* hprev = hbuf + (t & 1) * (B_*H_);
    ushort*       hnext = hbuf + ((t & 1) ^ 1) * (B_*H_);

    // ---- hh GEMM on top of xp: this wave's K-quarter over bg's slabs ----
    #pragma unroll
    for (int i = 0; i < 8; ++i){
      int k0 = wave*256 + i*32 + quad*8;
      bf16x8 b = ldh8(hprev + (size_t)(bg*64 + (k0 >> 4))*256 + c16*16 + (k0 & 15));
      #pragma unroll
      for (int mt = 0; mt < 4; ++mt)
        acc[mt] = __builtin_amdgcn_mfma_f32_16x16x32_bf16(whhf[mt][i], b, acc[mt], 0,0,0);
    }

    // ---- per-wave partials -> LDS. D: row = gate m = quad*4+r, col = batch c16
    #pragma unroll
    for (int mt = 0; mt < 4; ++mt)
      #pragma unroll
      for (int r = 0; r < 4; ++r)
        gates_s[wave][mt*16 + quad*4 + r][c16] = acc[mt][r];
    __syncthreads();

    // ---- nonlinearity + state update ----
    {
      float gsum[4];
      #pragma unroll
      for (int g = 0; g < 4; ++g){
        float s = bsum[g];
        #pragma unroll
        for (int q = 0; q < 4; ++q) s += gates_s[q][g*16 + uu][nn];
        gsum[g] = s;
      }
      float iv = sigm(gsum[0]), fv = sigm(gsum[1]), gv = tanh_(gsum[2]), ov = sigm(gsum[3]);
      float cn = fv*cstate + iv*gv;
      cstate = cn;
      float hn = ov*tanh_(cn);
      // coalesced slab store: addr = slab(cg,bg) + tid (layout [n][k])
      __hip_atomic_store(hnext + (size_t)(bg*64 + cg)*256 + tid, f2b(hn),
                         __ATOMIC_RELAXED, __HIP_MEMORY_SCOPE_AGENT);
      if (t == S_-1){
        out[(bg*16 + nn)*H_ + cg*16 + uu]          = hn;   // h_n
        out[B_*H_ + (bg*16 + nn)*H_ + cg*16 + uu]  = cn;   // c_n
      }
    }

    if (t < S_-1){
      // drain own h store to the coherence point, then arrive
      asm volatile("s_waitcnt vmcnt(0)" ::: "memory");
      __syncthreads();    // all stores drained + gates_s reads done
      if (tid == 0)
        __hip_atomic_store(&flags[bg*64 + cg], (unsigned)(t+1),
                           __ATOMIC_RELAXED, __HIP_MEMORY_SCOPE_AGENT);
      // prefetch xp(t+1) while peer blocks finish
      zacc();
      xp_gemm(t+1);
      // poll this bg's 64 flags (wave 0), sleep backoff
      if (tid < CG_){
        const unsigned target = (unsigned)(t+1);
        long guard = 0;
        while (__hip_atomic_load(&flags[bg*64 + tid], __ATOMIC_RELAXED,
                                 __HIP_MEMORY_SCOPE_AGENT) < target){
          __builtin_amdgcn_s_sleep(1);
          if (++guard > (1L<<22)) break;   // safety: never hang the harness
        }
      }
      __syncthreads();
    }
  }
}

extern "C" void kernel_launch(void* const* d_in, const int* in_sizes, int n_in,
                              void* d_out, int out_size, void* d_ws, size_t ws_size,
                              hipStream_t stream) {
  const float* X   = (const float*)d_in[0];
  const float* Wih = (const float*)d_in[1];
  const float* Whh = (const float*)d_in[2];
  const float* bih = (const float*)d_in[3];
  const float* bhh = (const float*)d_in[4];
  float* out = (float*)d_out;

  // ws layout: [0, 256KB) h slab double buffer, [256KB, +1KB) flags,
  //            [512KB, +35.7MB) X in bf16.
  char* ws = (char*)d_ws;
  const size_t HBUF_BYTES = 2ull * B_ * H_ * sizeof(ushort);   // 262144
  const size_t XB_OFF     = 524288;
  const size_t XB_BYTES   = (size_t)B_ * S_ * D_ * sizeof(ushort);  // 35.65 MB
  if (ws_size < XB_OFF + XB_BYTES) return;  // insufficient scratch: fail visibly

  ushort*   hbuf  = (ushort*)ws;
  unsigned* flags = (unsigned*)(ws + HBUF_BYTES);
  ushort*   Xb    = (ushort*)(ws + XB_OFF);

  hipMemsetAsync(d_ws, 0, XB_OFF, stream);   // zero h0 slabs + flags

  int n4 = B_*S_*D_/4;
  cvt_x<<<(n4 + 255)/256, 256, 0, stream>>>(X, Xb, n4);
  lstm_persist<<<GRID_, 256, 0, stream>>>(Wih, Whh, bih, bhh, Xb, hbuf, flags, out);
}

// Round 5
// 2708.674 us; speedup vs baseline: 4.3204x; 1.0847x over previous
//
#include <hip/hip_runtime.h>
#include <hip/hip_bf16.h>

// PBRNN LSTM: B=64, S=512, D=544, H=1024. out = [h_n; c_n] fp32 [2,64,1024].
//
// Round 5: self-timed dataflow h exchange (no barrier, no flags).
//  - h stored as tagged words: (step_tag<<16) | bf16(h). Consumers poll the
//    exact 32B fragments they need, validating the 16-bit tag in each 4B
//    word (4B atomicity binds tag to data). Removes the whole per-step
//    chain: store-drain RT + flag store + flag-poll RT + h-load RT -> ~1 RT.
//  - Skew pipelines through per-fragment instead of max-of-64 per barrier.
//  - 2-buffer safety: a block writes tag t+2 over its slab only after seeing
//    tag t+1 from all peer slabs; peers publish t+1 only after their
//    __syncthreads, i.e. after all their waves consumed the tag-t data.
//  - Partitioning as round 4: 256 blocks = 64 cg x 4 bg, W in VGPRs.

#define B_  64
#define S_  512
#define D_  544
#define H_  1024
#define CG_ 64
#define BG_ 4
#define GRID_ (CG_*BG_)

typedef __attribute__((ext_vector_type(8))) short bf16x8;
typedef __attribute__((ext_vector_type(4))) float f32x4;

__device__ inline ushort f2b(float x){
  unsigned u = __float_as_uint(x);
  u = (u + 0x7FFFu + ((u >> 16) & 1u)) >> 16;   // RNE
  return (ushort)u;
}

__device__ inline bf16x8 pack8(float4 a, float4 b){
  bf16x8 r;
  r[0]=(short)f2b(a.x); r[1]=(short)f2b(a.y); r[2]=(short)f2b(a.z); r[3]=(short)f2b(a.w);
  r[4]=(short)f2b(b.x); r[5]=(short)f2b(b.y); r[6]=(short)f2b(b.z); r[7]=(short)f2b(b.w);
  return r;
}

__device__ inline unsigned long long ld64a(const unsigned long long* q){
  return __hip_atomic_load(q, __ATOMIC_RELAXED, __HIP_MEMORY_SCOPE_AGENT);
}

__device__ inline float sigm(float x){ return __builtin_amdgcn_rcpf(1.f + __expf(-x)); }
__device__ inline float tanh_(float x){ return 1.f - 2.f*__builtin_amdgcn_rcpf(1.f + __expf(2.f*x)); }

__global__ void cvt_x(const float* __restrict__ x, ushort* __restrict__ xb, int n4){
  int i = blockIdx.x*256 + threadIdx.x;
  if (i >= n4) return;
  float4 v = ((const float4*)x)[i];
  ushort4 o;
  o.x=f2b(v.x); o.y=f2b(v.y); o.z=f2b(v.z); o.w=f2b(v.w);
  ((ushort4*)xb)[i] = o;
}

__global__ __launch_bounds__(256,1) void lstm_persist(
    const float* __restrict__ Wih, const float* __restrict__ Whh,
    const float* __restrict__ bih, const float* __restrict__ bhh,
    const ushort* __restrict__ Xb,
    unsigned* thbuf,       // [2][BG_][CG_][16 n][16 k] tagged words, pre-zeroed
    float* __restrict__ out)
{
  const int tid  = threadIdx.x;
  const int wave = tid >> 6;          // K-quarter for W_hh
  const int lane = tid & 63;
  const int c16  = lane & 15;
  const int quad = lane >> 4;
  const int cg   = blockIdx.x & (CG_-1);
  const int bg   = blockIdx.x >> 6;

  // per-wave gate partials: [wave][gate-row 0..63][batch 0..15] padded
  __shared__ float gates_s[4][64][17];

  // ---- W_hh A-fragments (VGPR-pinned): 4 M-tiles (gates i,f,g,o) x 8 K-iters
  bf16x8 whhf[4][8];
  #pragma unroll
  for (int mt = 0; mt < 4; ++mt){
    const size_t grow = (size_t)(mt*H_ + cg*16 + c16);
    #pragma unroll
    for (int i = 0; i < 8; ++i){
      int k = wave*256 + i*32 + quad*8;
      const float4* p = (const float4*)(Whh + grow*H_ + k);
      whhf[mt][i] = pack8(p[0], p[1]);
    }
  }
  // ---- W_ih A-fragments: K-iters it = wave, wave+4, ... < 17 ----
  bf16x8 wihf[4][5];
  #pragma unroll
  for (int mt = 0; mt < 4; ++mt){
    const size_t grow = (size_t)(mt*H_ + cg*16 + c16);
    #pragma unroll
    for (int ii = 0; ii < 5; ++ii){
      int it = wave + 4*ii;
      if (it < 17){
        int k = it*32 + quad*8;
        const float4* p = (const float4*)(Wih + grow*D_ + k);
        wihf[mt][ii] = pack8(p[0], p[1]);
      }
    }
  }

  // ---- update mapping: thread owns (batch nn, col uu) ----
  const int uu = tid & 15;
  const int nn = tid >> 4;
  float bsum[4];
  #pragma unroll
  for (int g = 0; g < 4; ++g)
    bsum[g] = bih[g*H_ + cg*16 + uu] + bhh[g*H_ + cg*16 + uu];
  float cstate = 0.f;

  f32x4 acc[4];   // [gate tile]; holds xp(t), hh added on top

  auto zacc = [&]{
    #pragma unroll
    for (int mt = 0; mt < 4; ++mt) acc[mt] = (f32x4){0.f,0.f,0.f,0.f};
  };
  auto xp_gemm = [&](int t){
    #pragma unroll
    for (int ii = 0; ii < 5; ++ii){
      int it = wave + 4*ii;
      if (it < 17){
        int k = it*32 + quad*8;
        bf16x8 b = *(const bf16x8*)(Xb + ((size_t)(bg*16 + c16)*S_ + t)*D_ + k);
        #pragma unroll
        for (int mt = 0; mt < 4; ++mt)
          acc[mt] = __builtin_amdgcn_mfma_f32_16x16x32_bf16(wihf[mt][ii], b, acc[mt], 0,0,0);
      }
    }
  };

  zacc();
  xp_gemm(0);

  // consumer fragment word offset (excluding the i*512 term):
  // slab = bg*64 + wave*16 + i*2 + (quad>>1); word = slab*256 + c16*16 + (quad&1)*8
  const int obase = (bg*64 + wave*16 + (quad>>1))*256 + c16*16 + (quad&1)*8;

  for (int t = 0; t < S_; ++t){
    const unsigned* hp = thbuf + (t & 1) * (B_*H_);
    unsigned*       hn = thbuf + ((t & 1) ^ 1) * (B_*H_);

    // ---- 1. poll + hh GEMM: this wave's K-quarter, tag-validated ----
    {
      const unsigned tag = (unsigned)t & 0xffffu;
      const unsigned long long tmask = 0xffff0000ffff0000ull;
      const unsigned long long texp  = ((unsigned long long)tag << 16)
                                     | ((unsigned long long)tag << 48);
      unsigned long long q[8][4];
      // issue all 32 loads up-front (MLP: one RT covers all)
      #pragma unroll
      for (int i = 0; i < 8; ++i){
        const unsigned long long* p = (const unsigned long long*)(hp + obase + i*512);
        q[i][0] = ld64a(p);   q[i][1] = ld64a(p+1);
        q[i][2] = ld64a(p+2); q[i][3] = ld64a(p+3);
      }
      #pragma unroll
      for (int i = 0; i < 8; ++i){
        const unsigned long long* p = (const unsigned long long*)(hp + obase + i*512);
        long guard = 0;
        while ((((q[i][0]^texp)|(q[i][1]^texp)|(q[i][2]^texp)|(q[i][3]^texp)) & tmask) != 0ull){
          q[i][0] = ld64a(p);   q[i][1] = ld64a(p+1);
          q[i][2] = ld64a(p+2); q[i][3] = ld64a(p+3);
          if (++guard > (1L<<20)) break;   // safety: never hang the harness
        }
        union { unsigned u[4]; bf16x8 v8; } eb;
        #pragma unroll
        for (int w = 0; w < 4; ++w){
          unsigned lo = (unsigned)q[i][w];
          unsigned hi = (unsigned)(q[i][w] >> 32);
          eb.u[w] = (lo & 0xffffu) | (hi << 16);
        }
        #pragma unroll
        for (int mt = 0; mt < 4; ++mt)
          acc[mt] = __builtin_amdgcn_mfma_f32_16x16x32_bf16(whhf[mt][i], eb.v8, acc[mt], 0,0,0);
      }
    }

    // ---- 2. per-wave partials -> LDS ----
    #pragma unroll
    for (int mt = 0; mt < 4; ++mt)
      #pragma unroll
      for (int r = 0; r < 4; ++r)
        gates_s[wave][mt*16 + quad*4 + r][c16] = acc[mt][r];
    __syncthreads();

    // ---- 3. nonlinearity + state update + tagged h store ----
    {
      float gsum[4];
      #pragma unroll
      for (int g = 0; g < 4; ++g){
        float s = bsum[g];
        #pragma unroll
        for (int q2 = 0; q2 < 4; ++q2) s += gates_s[q2][g*16 + uu][nn];
        gsum[g] = s;
      }
      float iv = sigm(gsum[0]), fv = sigm(gsum[1]), gv = tanh_(gsum[2]), ov = sigm(gsum[3]);
      float cn = fv*cstate + iv*gv;
      cstate = cn;
      float hv = ov*tanh_(cn);
      // tagged coalesced store: word = (tag t+1)<<16 | bf16(h)
      unsigned word = (((unsigned)(t+1) & 0xffffu) << 16) | (unsigned)f2b(hv);
      __hip_atomic_store(hn + (size_t)(bg*64 + cg)*256 + tid, word,
                         __ATOMIC_RELAXED, __HIP_MEMORY_SCOPE_AGENT);
      if (t == S_-1){
        out[(bg*16 + nn)*H_ + cg*16 + uu]          = hv;   // h_n
        out[B_*H_ + (bg*16 + nn)*H_ + cg*16 + uu]  = cn;   // c_n
      }
    }
    __syncthreads();   // protect gates_s for next step's partial writes

    // ---- 4. prefetch xp(t+1) while peers consume h(t+1) ----
    if (t < S_-1){
      zacc();
      xp_gemm(t+1);
    }
  }
}

extern "C" void kernel_launch(void* const* d_in, const int* in_sizes, int n_in,
                              void* d_out, int out_size, void* d_ws, size_t ws_size,
                              hipStream_t stream) {
  const float* X   = (const float*)d_in[0];
  const float* Wih = (const float*)d_in[1];
  const float* Whh = (const float*)d_in[2];
  const float* bih = (const float*)d_in[3];
  const float* bhh = (const float*)d_in[4];
  float* out = (float*)d_out;

  // ws layout: [0, 512KB) tagged h double buffer, [512KB, +35.7MB) X bf16.
  char* ws = (char*)d_ws;
  const size_t THBUF_BYTES = 2ull * B_ * H_ * sizeof(unsigned);     // 524288
  const size_t XB_OFF      = THBUF_BYTES;
  const size_t XB_BYTES    = (size_t)B_ * S_ * D_ * sizeof(ushort); // 35.65 MB
  if (ws_size < XB_OFF + XB_BYTES) return;  // insufficient scratch: fail visibly

  unsigned* thbuf = (unsigned*)ws;
  ushort*   Xb    = (ushort*)(ws + XB_OFF);

  hipMemsetAsync(d_ws, 0, THBUF_BYTES, stream);   // tags=0, h0=0

  int n4 = B_*S_*D_/4;
  cvt_x<<<(n4 + 255)/256, 256, 0, stream>>>(X, Xb, n4);
  lstm_persist<<<GRID_, 256, 0, stream>>>(Wih, Whh, bih, bhh, Xb, thbuf, out);
}

// Round 6
// 2342.374 us; speedup vs baseline: 4.9961x; 1.1564x over previous
//
#include <hip/hip_runtime.h>
#include <hip/hip_bf16.h>

// PBRNN LSTM: B=64, S=512, D=544, H=1024. out = [h_n; c_n] fp32 [2,64,1024].
//
// Round 6: shave serial RTs off the self-timed (tagged-word) exchange.
//  - X(t+1) raw loads hoisted above poll(t): end-of-step xp MFMA has no
//    load latency on the critical path.
//  - Poll retries in parallel rounds per lane (8-bit stale mask): each
//    round = 1 LIC RT for ALL stale fragments (was serialized per fragment).
//  - gates_s double-buffered -> single __syncthreads per step (safety is
//    transitive through the tag protocol: reaching poll(t+2) implies every
//    peer validated our tag-(t+1) slab, which implies all our waves
//    finished reading gates_s[t&1]).
//  - XCD-affinity swizzle: bg=(blk&7)>>1, cg=(blk>>3)*2|(blk&1) -> each
//    bg's 64 blocks sit on 2 XCDs; shared X(t) slice fetched once per L2.

#define B_  64
#define S_  512
#define D_  544
#define H_  1024
#define CG_ 64
#define BG_ 4
#define GRID_ (CG_*BG_)

typedef __attribute__((ext_vector_type(8))) short bf16x8;
typedef __attribute__((ext_vector_type(4))) float f32x4;

__device__ inline ushort f2b(float x){
  unsigned u = __float_as_uint(x);
  u = (u + 0x7FFFu + ((u >> 16) & 1u)) >> 16;   // RNE
  return (ushort)u;
}

__device__ inline bf16x8 pack8(float4 a, float4 b){
  bf16x8 r;
  r[0]=(short)f2b(a.x); r[1]=(short)f2b(a.y); r[2]=(short)f2b(a.z); r[3]=(short)f2b(a.w);
  r[4]=(short)f2b(b.x); r[5]=(short)f2b(b.y); r[6]=(short)f2b(b.z); r[7]=(short)f2b(b.w);
  return r;
}

__device__ inline unsigned long long ld64a(const unsigned long long* q){
  return __hip_atomic_load(q, __ATOMIC_RELAXED, __HIP_MEMORY_SCOPE_AGENT);
}

__device__ inline float sigm(float x){ return __builtin_amdgcn_rcpf(1.f + __expf(-x)); }
__device__ inline float tanh_(float x){ return 1.f - 2.f*__builtin_amdgcn_rcpf(1.f + __expf(2.f*x)); }

__global__ void cvt_x(const float* __restrict__ x, ushort* __restrict__ xb, int n4){
  int i = blockIdx.x*256 + threadIdx.x;
  if (i >= n4) return;
  float4 v = ((const float4*)x)[i];
  ushort4 o;
  o.x=f2b(v.x); o.y=f2b(v.y); o.z=f2b(v.z); o.w=f2b(v.w);
  ((ushort4*)xb)[i] = o;
}

__global__ __launch_bounds__(256,1) void lstm_persist(
    const float* __restrict__ Wih, const float* __restrict__ Whh,
    const float* __restrict__ bih, const float* __restrict__ bhh,
    const ushort* __restrict__ Xb,
    unsigned* thbuf,       // [2][BG_][CG_][16 n][16 k] tagged words, pre-zeroed
    float* __restrict__ out)
{
  const int tid  = threadIdx.x;
  const int wave = tid >> 6;          // K-quarter for W_hh
  const int lane = tid & 63;
  const int c16  = lane & 15;
  const int quad = lane >> 4;
  // XCD-affinity swizzle: XCD = blockIdx%8 (round-robin dispatch)
  const int bg   = (blockIdx.x & 7) >> 1;
  const int cg   = ((blockIdx.x >> 3) << 1) | (blockIdx.x & 1);

  // double-buffered per-wave gate partials
  __shared__ float gates_s[2][4][64][17];

  // ---- W_hh A-fragments (VGPR-pinned): 4 M-tiles (gates i,f,g,o) x 8 K-iters
  bf16x8 whhf[4][8];
  #pragma unroll
  for (int mt = 0; mt < 4; ++mt){
    const size_t grow = (size_t)(mt*H_ + cg*16 + c16);
    #pragma unroll
    for (int i = 0; i < 8; ++i){
      int k = wave*256 + i*32 + quad*8;
      const float4* p = (const float4*)(Whh + grow*H_ + k);
      whhf[mt][i] = pack8(p[0], p[1]);
    }
  }
  // ---- W_ih A-fragments: K-iters it = wave, wave+4, ... < 17 ----
  bf16x8 wihf[4][5];
  #pragma unroll
  for (int mt = 0; mt < 4; ++mt){
    const size_t grow = (size_t)(mt*H_ + cg*16 + c16);
    #pragma unroll
    for (int ii = 0; ii < 5; ++ii){
      int it = wave + 4*ii;
      if (it < 17){
        int k = it*32 + quad*8;
        const float4* p = (const float4*)(Wih + grow*D_ + k);
        wihf[mt][ii] = pack8(p[0], p[1]);
      }
    }
  }

  // ---- update mapping: thread owns (batch nn, col uu) ----
  const int uu = tid & 15;
  const int nn = tid >> 4;
  float bsum[4];
  #pragma unroll
  for (int g = 0; g < 4; ++g)
    bsum[g] = bih[g*H_ + cg*16 + uu] + bhh[g*H_ + cg*16 + uu];
  float cstate = 0.f;

  f32x4 acc[4];      // [gate tile]
  bf16x8 xraw[5];    // raw X fragments for the NEXT xp_gemm (preloaded)

  auto zacc = [&]{
    #pragma unroll
    for (int mt = 0; mt < 4; ++mt) acc[mt] = (f32x4){0.f,0.f,0.f,0.f};
  };
  auto ldx = [&](int t){            // issue raw X loads (no compute dep)
    if (t >= S_) t = S_-1;          // clamp: avoid OOB on the tail prefetch
    #pragma unroll
    for (int ii = 0; ii < 5; ++ii){
      int it = wave + 4*ii;
      if (it < 17)
        xraw[ii] = *(const bf16x8*)(Xb + ((size_t)(bg*16 + c16)*S_ + t)*D_ + it*32 + quad*8);
    }
  };
  auto xp_mfma = [&]{               // consume xraw (loads long since landed)
    #pragma unroll
    for (int ii = 0; ii < 5; ++ii){
      int it = wave + 4*ii;
      if (it < 17){
        #pragma unroll
        for (int mt = 0; mt < 4; ++mt)
          acc[mt] = __builtin_amdgcn_mfma_f32_16x16x32_bf16(wihf[mt][ii], xraw[ii], acc[mt], 0,0,0);
      }
    }
  };

  // prologue: xp(0) computed, X(1) in flight
  ldx(0);
  zacc();
  xp_mfma();
  ldx(1);

  // consumer fragment word offset (excluding the i*512 term):
  // slab = bg*64 + wave*16 + i*2 + (quad>>1); word = slab*256 + c16*16 + (quad&1)*8
  const int obase = (bg*64 + wave*16 + (quad>>1))*256 + c16*16 + (quad&1)*8;

  for (int t = 0; t < S_; ++t){
    const unsigned* hp = thbuf + (t & 1) * (B_*H_);
    unsigned*       hn = thbuf + ((t & 1) ^ 1) * (B_*H_);

    // ---- 1. poll h(t) fragments: parallel retry rounds (per-lane mask) ----
    unsigned long long q[8][4];
    {
      const unsigned tag = (unsigned)t & 0xffffu;
      const unsigned long long tmask = 0xffff0000ffff0000ull;
      const unsigned long long texp  = ((unsigned long long)tag << 16)
                                     | ((unsigned long long)tag << 48);
      const unsigned long long* pb[8];
      #pragma unroll
      for (int i = 0; i < 8; ++i){
        pb[i] = (const unsigned long long*)(hp + obase + i*512);
        q[i][0] = ld64a(pb[i]);   q[i][1] = ld64a(pb[i]+1);
        q[i][2] = ld64a(pb[i]+2); q[i][3] = ld64a(pb[i]+3);
      }
      unsigned stale = 0xffu;
      long rounds = 0;
      while (stale){
        unsigned ns = 0;
        #pragma unroll
        for (int i = 0; i < 8; ++i){
          if (stale & (1u << i)){
            unsigned long long d = ((q[i][0]^texp)|(q[i][1]^texp)
                                   |(q[i][2]^texp)|(q[i][3]^texp)) & tmask;
            if (d != 0ull){
              q[i][0] = ld64a(pb[i]);   q[i][1] = ld64a(pb[i]+1);
              q[i][2] = ld64a(pb[i]+2); q[i][3] = ld64a(pb[i]+3);
              ns |= (1u << i);
            }
          }
        }
        stale = ns;
        if (++rounds > (1L<<20)) break;   // safety: never hang the harness
      }
    }
    // ---- 2. extract + hh MFMA (wave reconverged) ----
    #pragma unroll
    for (int i = 0; i < 8; ++i){
      union { unsigned u[4]; bf16x8 v8; } eb;
      #pragma unroll
      for (int w = 0; w < 4; ++w){
        unsigned lo = (unsigned)q[i][w];
        unsigned hi = (unsigned)(q[i][w] >> 32);
        eb.u[w] = (lo & 0xffffu) | (hi << 16);
      }
      #pragma unroll
      for (int mt = 0; mt < 4; ++mt)
        acc[mt] = __builtin_amdgcn_mfma_f32_16x16x32_bf16(whhf[mt][i], eb.v8, acc[mt], 0,0,0);
    }

    // ---- 3. per-wave partials -> LDS (ping-pong buffer) ----
    #pragma unroll
    for (int mt = 0; mt < 4; ++mt)
      #pragma unroll
      for (int r = 0; r < 4; ++r)
        gates_s[t & 1][wave][mt*16 + quad*4 + r][c16] = acc[mt][r];
    __syncthreads();

    // ---- 4. nonlinearity + state update + tagged h store ----
    {
      float gsum[4];
      #pragma unroll
      for (int g = 0; g < 4; ++g){
        float s = bsum[g];
        #pragma unroll
        for (int q2 = 0; q2 < 4; ++q2) s += gates_s[t & 1][q2][g*16 + uu][nn];
        gsum[g] = s;
      }
      float iv = sigm(gsum[0]), fv = sigm(gsum[1]), gv = tanh_(gsum[2]), ov = sigm(gsum[3]);
      float cn = fv*cstate + iv*gv;
      cstate = cn;
      float hv = ov*tanh_(cn);
      unsigned word = (((unsigned)(t+1) & 0xffffu) << 16) | (unsigned)f2b(hv);
      __hip_atomic_store(hn + (size_t)(bg*64 + cg)*256 + tid, word,
                         __ATOMIC_RELAXED, __HIP_MEMORY_SCOPE_AGENT);
      if (t == S_-1){
        out[(bg*16 + nn)*H_ + cg*16 + uu]          = hv;   // h_n
        out[B_*H_ + (bg*16 + nn)*H_ + cg*16 + uu]  = cn;   // c_n
      }
    }

    // ---- 5. xp(t+1) from preloaded xraw; issue X(t+2) loads ----
    if (t < S_-1){
      zacc();
      xp_mfma();     // X(t+1), already resident
      ldx(t + 2);    // in flight across poll(t+1)
    }
  }
}

extern "C" void kernel_launch(void* const* d_in, const int* in_sizes, int n_in,
                              void* d_out, int out_size, void* d_ws, size_t ws_size,
                              hipStream_t stream) {
  const float* X   = (const float*)d_in[0];
  const float* Wih = (const float*)d_in[1];
  const float* Whh = (const float*)d_in[2];
  const float* bih = (const float*)d_in[3];
  const float* bhh = (const float*)d_in[4];
  float* out = (float*)d_out;

  // ws layout: [0, 512KB) tagged h double buffer, [512KB, +35.7MB) X bf16.
  char* ws = (char*)d_ws;
  const size_t THBUF_BYTES = 2ull * B_ * H_ * sizeof(unsigned);     // 524288
  const size_t XB_OFF      = THBUF_BYTES;
  const size_t XB_BYTES    = (size_t)B_ * S_ * D_ * sizeof(ushort); // 35.65 MB
  if (ws_size < XB_OFF + XB_BYTES) return;  // insufficient scratch: fail visibly

  unsigned* thbuf = (unsigned*)ws;
  ushort*   Xb    = (ushort*)(ws + XB_OFF);

  hipMemsetAsync(d_ws, 0, THBUF_BYTES, stream);   // tags=0, h0=0

  int n4 = B_*S_*D_/4;
  cvt_x<<<(n4 + 255)/256, 256, 0, stream>>>(X, Xb, n4);
  lstm_persist<<<GRID_, 256, 0, stream>>>(Wih, Whh, bih, bhh, Xb, thbuf, out);
}